// Round 2
// baseline (3837.516 us; speedup 1.0000x reference)
//
#include <hip/hip_runtime.h>
#include <stdint.h>

#define BQ    256      // queries
#define NG    196608   // gallery rows
#define D3    1536     // dim
#define KK    32       // top-k
#define NBLK  384      // gallery blocks
#define RPB   512      // rows per block
#define SUBR  64       // rows per subtile
#define NSUB  8        // RPB/SUBR
#define KSTEP 32       // k-dim step
#define NKS   48       // D3/KSTEP
#define NCAND (NBLK*KK) // 12288 candidates per query

// Sorted-descending top-K insert, fully static indexing (no scratch).
__device__ __forceinline__ void topk_insert(float (&bs)[KK], int (&bi)[KK],
                                            float s, int idx) {
    float cs = s; int ci = idx;
#pragma unroll
    for (int m = 0; m < KK; ++m) {
        const bool sw = cs > bs[m];
        const float ts = sw ? bs[m] : cs;
        const int   ti = sw ? bi[m] : ci;
        bs[m] = sw ? cs : bs[m];
        bi[m] = sw ? ci : bi[m];
        cs = ts; ci = ti;
    }
}

// Kernel A: per-block fp32 GEMM (512 rows x 256 queries) + per-query block top-32.
__global__ __launch_bounds__(256, 2)
void score_block_topk(const float* __restrict__ Q, const float* __restrict__ G,
                      const int* __restrict__ M,
                      float* __restrict__ cand_s, int* __restrict__ cand_i) {
    // LDS: Qs[KSTEP][256] (32KB) + Gs[KSTEP][64] (8KB), union'd with Sl[256][65] (66.56KB)
    __shared__ float smem[16640];
    float* Qs = smem;               // [KSTEP][256]
    float* Gs = smem + KSTEP * 256; // [KSTEP][64]
    float* Sl = smem;               // [256][65] (reuses Qs/Gs region)

    const int blk  = blockIdx.x;
    const int tid  = threadIdx.x;
    const int row0 = blk * RPB;
    const int tq   = tid >> 3; // 0..31 -> queries tq*8..+8
    const int tr   = tid & 7;  // 0..7  -> rows tr*8..+8

    float bs[KK]; int bi[KK];
#pragma unroll
    for (int m = 0; m < KK; ++m) { bs[m] = -__builtin_inff(); bi[m] = -1; }

    for (int sub = 0; sub < NSUB; ++sub) {
        const int srow = row0 + sub * SUBR;
        float acc[8][8];
#pragma unroll
        for (int i = 0; i < 8; ++i)
#pragma unroll
            for (int j = 0; j < 8; ++j) acc[i][j] = 0.0f;

        for (int ks = 0; ks < NKS; ++ks) {
            const int k0 = ks * KSTEP;
            __syncthreads(); // protect smem from previous phase readers
            // ---- stage Q slice: Qs[kk][q] = Q[q][k0+kk]
            {
                const int part = tid & 7;  // k chunk of 4
                const int qb   = tid >> 3; // 0..31
#pragma unroll
                for (int rep = 0; rep < 8; ++rep) {
                    const int q = rep * 32 + qb;
                    const float4 v = *(const float4*)(Q + (size_t)q * D3 + k0 + part * 4);
                    const int kb = part * 4;
                    Qs[(kb + 0) * 256 + q] = v.x;
                    Qs[(kb + 1) * 256 + q] = v.y;
                    Qs[(kb + 2) * 256 + q] = v.z;
                    Qs[(kb + 3) * 256 + q] = v.w;
                }
            }
            // ---- stage G slice: Gs[kk][r] = G[srow+r][k0+kk]
            {
                const int r    = tid >> 2; // 0..63
                const int part = tid & 3;  // k chunk of 8
                const float* gp = G + (size_t)(srow + r) * D3 + k0 + part * 8;
                const float4 a = *(const float4*)gp;
                const float4 b = *(const float4*)(gp + 4);
                const int kb = part * 8;
                Gs[(kb + 0) * 64 + r] = a.x;
                Gs[(kb + 1) * 64 + r] = a.y;
                Gs[(kb + 2) * 64 + r] = a.z;
                Gs[(kb + 3) * 64 + r] = a.w;
                Gs[(kb + 4) * 64 + r] = b.x;
                Gs[(kb + 5) * 64 + r] = b.y;
                Gs[(kb + 6) * 64 + r] = b.z;
                Gs[(kb + 7) * 64 + r] = b.w;
            }
            __syncthreads();
            // ---- 8x8 register-tile FMA
#pragma unroll 8
            for (int kk = 0; kk < KSTEP; ++kk) {
                const float4 q0 = *(const float4*)&Qs[kk * 256 + tq * 8];
                const float4 q1 = *(const float4*)&Qs[kk * 256 + tq * 8 + 4];
                const float4 g0 = *(const float4*)&Gs[kk * 64 + tr * 8];
                const float4 g1 = *(const float4*)&Gs[kk * 64 + tr * 8 + 4];
                const float qv[8] = {q0.x, q0.y, q0.z, q0.w, q1.x, q1.y, q1.z, q1.w};
                const float gv[8] = {g0.x, g0.y, g0.z, g0.w, g1.x, g1.y, g1.z, g1.w};
#pragma unroll
                for (int i = 0; i < 8; ++i)
#pragma unroll
                    for (int j = 0; j < 8; ++j)
                        acc[i][j] = __builtin_fmaf(qv[i], gv[j], acc[i][j]);
            }
        }
        __syncthreads(); // all done reading Qs/Gs
        // ---- mask (int32 bool) + transpose scores into Sl[q][r]
#pragma unroll
        for (int i = 0; i < 8; ++i) {
            const int q = tq * 8 + i;
            const int* mp_ = M + (size_t)q * NG + srow + tr * 8;
            const int4 ma = *(const int4*)mp_;
            const int4 mb = *(const int4*)(mp_ + 4);
            const int mv[8] = {ma.x, ma.y, ma.z, ma.w, mb.x, mb.y, mb.z, mb.w};
#pragma unroll
            for (int j = 0; j < 8; ++j) {
                Sl[q * 65 + tr * 8 + j] = mv[j] ? -__builtin_inff() : acc[i][j];
            }
        }
        __syncthreads();
        // ---- thread tid scans query tid's 64 scores (2-way bank alias = free)
        {
            const float* rowp = Sl + tid * 65;
            for (int r = 0; r < SUBR; ++r) {
                const float s = rowp[r];
                if (s > bs[KK - 1]) topk_insert(bs, bi, s, srow + r);
            }
        }
        // next subtile's loop-top __syncthreads protects Sl before restaging
    }
    // ---- emit per-(query, block) top-32
    float* os = cand_s + ((size_t)tid * NBLK + blk) * KK;
    int*   oi = cand_i + ((size_t)tid * NBLK + blk) * KK;
#pragma unroll
    for (int m = 0; m < KK; ++m) { os[m] = bs[m]; oi[m] = bi[m]; }
}

// Kernel B: one wave per query, merge 12288 candidates -> final top-32.
__global__ __launch_bounds__(64)
void merge_topk(const float* __restrict__ cand_s, const int* __restrict__ cand_i,
                float* __restrict__ out) {
    const int q = blockIdx.x;
    const int l = threadIdx.x;
    const float* cs = cand_s + (size_t)q * NCAND;
    const int*   ci = cand_i + (size_t)q * NCAND;

    float bs[KK]; int bi[KK];
#pragma unroll
    for (int m = 0; m < KK; ++m) { bs[m] = -__builtin_inff(); bi[m] = -1; }

    for (int t = l; t < NCAND; t += 64) {
        const float s = cs[t];
        if (s > bs[KK - 1]) topk_insert(bs, bi, s, ci[t]);
    }

    __shared__ float Ls[64 * KK];
    __shared__ int   Li[64 * KK];
#pragma unroll
    for (int m = 0; m < KK; ++m) { Ls[l * KK + m] = bs[m]; Li[l * KK + m] = bi[m]; }
    __syncthreads();

    for (int r = 0; r < KK; ++r) {
        float ms = -__builtin_inff();
        int   mi = 0x7fffffff;
        int   mp = -1;
#pragma unroll
        for (int j = 0; j < KK; ++j) {
            const int p = l + 64 * j; // stride-64: 2-way bank alias = free
            const float s = Ls[p];
            const int  id = Li[p];
            if (s > ms || (s == ms && id < mi)) { ms = s; mi = id; mp = p; }
        }
#pragma unroll
        for (int off = 32; off >= 1; off >>= 1) {
            const float s2 = __shfl_down(ms, off);
            const int   i2 = __shfl_down(mi, off);
            const int   p2 = __shfl_down(mp, off);
            if (s2 > ms || (s2 == ms && i2 < mi)) { ms = s2; mi = i2; mp = p2; }
        }
        if (l == 0) {
            out[(size_t)q * KK + r] = (float)mi;                    // best_i as float
            out[(size_t)BQ * KK + (size_t)q * KK + r] = ms;          // best_s
            if (mp >= 0) Ls[mp] = -__builtin_inff();                 // invalidate winner
        }
        __syncthreads();
    }
}

extern "C" void kernel_launch(void* const* d_in, const int* in_sizes, int n_in,
                              void* d_out, int out_size, void* d_ws, size_t ws_size,
                              hipStream_t stream) {
    const float* Q = (const float*)d_in[0];
    const float* G = (const float*)d_in[1];
    const int*   M = (const int*)d_in[2];
    // d_in[3] = k (fixed at 32 by the harness inputs)

    float* cand_s = (float*)d_ws;
    int*   cand_i = (int*)((char*)d_ws + (size_t)BQ * NBLK * KK * sizeof(float));
    float* out    = (float*)d_out;

    hipLaunchKernelGGL(score_block_topk, dim3(NBLK), dim3(256), 0, stream,
                       Q, G, M, cand_s, cand_i);
    hipLaunchKernelGGL(merge_topk, dim3(BQ), dim3(64), 0, stream,
                       cand_s, cand_i, out);
}

// Round 4
// 956.898 us; speedup vs baseline: 4.0104x; 4.0104x over previous
//
#include <hip/hip_runtime.h>
#include <stdint.h>

#define BQ    256      // queries
#define NG    196608   // gallery rows
#define D3    1536     // dim
#define KK    32       // final top-k
#define KBP   16       // per-block top-k
#define WB    512      // gallery blocks
#define RPB   384      // rows per block
#define NR    128      // rows per N-step
#define NSTEPS 3       // RPB/NR
#define BK    64       // k-dim staging step
#define NKS   24       // D3/BK
#define NCAND (WB*KBP) // 8192 candidates per query
#define C64   64       // rescore candidate count

typedef short  s16x8 __attribute__((ext_vector_type(8)));
typedef float  f32x4 __attribute__((ext_vector_type(4)));

#define NEG_INF (-__builtin_inff())

// ---------- fp32 -> bf16 (RNE) ----------
__device__ __forceinline__ unsigned f2bf1(float x) {
    unsigned u = __builtin_bit_cast(unsigned, x);
    return (u + 0x7fffu + ((u >> 16) & 1u)) >> 16;
}
__device__ __forceinline__ unsigned pack2(float lo, float hi) {
    return (f2bf1(hi) << 16) | f2bf1(lo);
}

// ---------- sorted-descending top-K inserts (static indexing) ----------
__device__ __forceinline__ void topkb_insert(float (&bs)[KBP], int (&bi)[KBP],
                                             float s, int idx) {
    float cs = s; int ci = idx;
#pragma unroll
    for (int m = 0; m < KBP; ++m) {
        const bool sw = cs > bs[m];
        const float ts = sw ? bs[m] : cs;
        const int   ti = sw ? bi[m] : ci;
        bs[m] = sw ? cs : bs[m];
        bi[m] = sw ? ci : bi[m];
        cs = ts; ci = ti;
    }
}
__device__ __forceinline__ void top8_insert(float (&bs)[8], int (&bi)[8],
                                            float s, int idx) {
    float cs = s; int ci = idx;
#pragma unroll
    for (int m = 0; m < 8; ++m) {
        const bool sw = cs > bs[m];
        const float ts = sw ? bs[m] : cs;
        const int   ti = sw ? bi[m] : ci;
        bs[m] = sw ? cs : bs[m];
        bi[m] = sw ? ci : bi[m];
        cs = ts; ci = ti;
    }
}

// ---------- Kernel 0: Q fp32 -> bf16 ----------
__global__ __launch_bounds__(256)
void cvt_q(const float* __restrict__ Q, unsigned short* __restrict__ Qbf) {
    const int i = (blockIdx.x * 256 + threadIdx.x) * 8;
    const float4 a = *(const float4*)(Q + i);
    const float4 b = *(const float4*)(Q + i + 4);
    uint4 v;
    v.x = pack2(a.x, a.y); v.y = pack2(a.z, a.w);
    v.z = pack2(b.x, b.y); v.w = pack2(b.z, b.w);
    *(uint4*)(Qbf + i) = v;
}

// ---------- Kernel A: bf16 MFMA scoring + per-block top-16 ----------
// LDS: Qs bf16[256 q][64 k] @0 (32KB, XOR-swizzled rows), Gs bf16[128 r][64 k] @32768 (16KB).
// Epilogue overlay: per-wave Sl[64 q][33] f32 @ w*8448.
__global__ __launch_bounds__(256, 2)
void score_mfma(const unsigned short* __restrict__ Qbf, const float* __restrict__ G,
                const int* __restrict__ M,
                float* __restrict__ cand_s, int* __restrict__ cand_i) {
    __shared__ __align__(16) char lds[49152];
    const int blk = blockIdx.x, t = threadIdx.x;
    const int w = t >> 6, l = t & 63;
    const int l15 = l & 15, l4 = l >> 4;

    float bs[KBP]; int bi[KBP];
#pragma unroll
    for (int m = 0; m < KBP; ++m) { bs[m] = NEG_INF; bi[m] = -1; }

    const int grow_blk = blk * RPB;

    for (int ns = 0; ns < NSTEPS; ++ns) {
        const int grow0 = grow_blk + ns * NR;
        f32x4 acc[4][8];
#pragma unroll
        for (int qt = 0; qt < 4; ++qt)
#pragma unroll
            for (int rt = 0; rt < 8; ++rt) acc[qt][rt] = (f32x4)0.0f;

        for (int ks = 0; ks < NKS; ++ks) {
            const int k0 = ks * BK;
            __syncthreads(); // previous phase done reading LDS
            // ---- stage Qs: thread t = query row t, 128B (XOR-swizzled)
            {
                const unsigned short* src = Qbf + (size_t)t * D3 + k0;
                const int rb = t * 128, rx = (t & 7) << 4;
#pragma unroll
                for (int c = 0; c < 8; ++c) {
                    const uint4 v = *(const uint4*)(src + c * 8);
                    *(uint4*)(lds + ((rb + c * 16) ^ rx)) = v;
                }
            }
            // ---- stage Gs: 2 threads/row, fp32 load + RNE cvt + swizzled store
            {
                const int r = t >> 1, h = t & 1;
                const float* src = G + (size_t)(grow0 + r) * D3 + k0 + h * 32;
                float4 f[8];
#pragma unroll
                for (int c = 0; c < 8; ++c) f[c] = *(const float4*)(src + c * 4);
                const int ro = r * 128 + h * 64, rx = (r & 7) << 4;
#pragma unroll
                for (int c2 = 0; c2 < 4; ++c2) {
                    uint4 v;
                    v.x = pack2(f[2 * c2].x, f[2 * c2].y);
                    v.y = pack2(f[2 * c2].z, f[2 * c2].w);
                    v.z = pack2(f[2 * c2 + 1].x, f[2 * c2 + 1].y);
                    v.w = pack2(f[2 * c2 + 1].z, f[2 * c2 + 1].w);
                    *(uint4*)(lds + 32768 + ((ro + c2 * 16) ^ rx)) = v;
                }
            }
            __syncthreads();
            // ---- MFMA (16x16x32 bf16, m89-verified layouts)
#pragma unroll
            for (int sk = 0; sk < 2; ++sk) {
                const int koff = sk * 64 + l4 * 16; // byte offset of lane's k in 128B row
                s16x8 a[4];
#pragma unroll
                for (int qt = 0; qt < 4; ++qt) {
                    const int row = w * 64 + qt * 16 + l15;
                    a[qt] = *(const s16x8*)(lds + ((row * 128 + koff) ^ ((row & 7) << 4)));
                }
#pragma unroll
                for (int rt = 0; rt < 8; ++rt) {
                    const int row = rt * 16 + l15;
                    const s16x8 b = *(const s16x8*)(lds + 32768 +
                                     ((row * 128 + koff) ^ ((row & 7) << 4)));
#pragma unroll
                    for (int qt = 0; qt < 4; ++qt)
                        acc[qt][rt] = __builtin_amdgcn_mfma_f32_16x16x32_bf16(
                            a[qt], b, acc[qt][rt], 0, 0, 0);
                }
            }
        }
        __syncthreads(); // all waves done reading Qs/Gs; reuse LDS as per-wave slabs
        // ---- epilogue: per-wave private slab, dump + mask + top-k scan
        float* Slw = (float*)(lds + w * 8448); // [64][33]
        const int q = t; // global query index
        const int* mrow = M + (size_t)q * NG + grow0;
#pragma unroll
        for (int rs = 0; rs < 4; ++rs) {
            // dump 64q x 32r (C/D: col n = lane&15, row m = (lane>>4)*4+reg)
#pragma unroll
            for (int qt = 0; qt < 4; ++qt)
#pragma unroll
                for (int r2 = 0; r2 < 2; ++r2)
#pragma unroll
                    for (int reg = 0; reg < 4; ++reg) {
                        const int qloc = qt * 16 + l4 * 4 + reg;
                        const int nloc = r2 * 16 + l15;
                        Slw[qloc * 33 + nloc] = acc[qt][rs * 2 + r2][reg];
                    }
            __asm__ volatile("s_waitcnt lgkmcnt(0)" ::: "memory");
            // mask bits for this lane's query, 32 rows
            const int row0 = rs * 32;
            unsigned mv32 = 0;
#pragma unroll
            for (int c = 0; c < 8; ++c) {
                const int4 mm = *(const int4*)(mrow + row0 + c * 4);
                mv32 |= (mm.x ? 1u : 0u) << (c * 4);
                mv32 |= (mm.y ? 1u : 0u) << (c * 4 + 1);
                mv32 |= (mm.z ? 1u : 0u) << (c * 4 + 2);
                mv32 |= (mm.w ? 1u : 0u) << (c * 4 + 3);
            }
            const float* sp = Slw + l * 33;
            for (int j = 0; j < 32; ++j) {
                const float s = sp[j];
                if (s > bs[KBP - 1] && !((mv32 >> j) & 1u))
                    topkb_insert(bs, bi, s, grow0 + row0 + j);
            }
            __asm__ volatile("s_waitcnt lgkmcnt(0)" ::: "memory"); // reads done before next dump
        }
    }
    // ---- emit per-(query, block) top-16
    float* os = cand_s + ((size_t)t * WB + blk) * KBP;
    int*   oi = cand_i + ((size_t)t * WB + blk) * KBP;
#pragma unroll
    for (int m = 0; m < KBP; ++m) { os[m] = bs[m]; oi[m] = bi[m]; }
}

// ---------- Kernel B: merge -> bf16-top-64 -> fp32 rescore -> final top-32 ----------
__global__ __launch_bounds__(256)
void merge_rescore(const float* __restrict__ cand_s, const int* __restrict__ cand_i,
                   const float* __restrict__ Q, const float* __restrict__ G,
                   float* __restrict__ out) {
    __shared__ float Ls[2048];
    __shared__ int   Li[2048];
    __shared__ int   sel[C64];
    __shared__ float Fs[C64];
    const int q = blockIdx.x, t = threadIdx.x, l = t & 63, w = t >> 6;
    const float* cs = cand_s + (size_t)q * NCAND;
    const int*   ci = cand_i + (size_t)q * NCAND;

    // phase 1: per-thread top-8 over 32 strided candidates
    float b8[8]; int i8[8];
#pragma unroll
    for (int m = 0; m < 8; ++m) { b8[m] = NEG_INF; i8[m] = -1; }
    for (int j = 0; j < NCAND / 256; ++j) {
        const float s = cs[t + 256 * j];
        if (s > b8[7]) top8_insert(b8, i8, s, ci[t + 256 * j]);
    }
#pragma unroll
    for (int m = 0; m < 8; ++m) { Ls[t * 8 + m] = b8[m]; Li[t * 8 + m] = i8[m]; }
    __syncthreads();

    // phase 2: 64 argmax rounds by wave 0 (tie-break: lower index)
    for (int r = 0; r < C64; ++r) {
        if (t < 64) {
            float ms = NEG_INF; int mi = 0x7fffffff, mp = -1;
            for (int jj = 0; jj < 32; ++jj) {
                const float s = Ls[l + 64 * jj];
                const int  id = Li[l + 64 * jj];
                if (s > ms || (s == ms && id < mi)) { ms = s; mi = id; mp = l + 64 * jj; }
            }
#pragma unroll
            for (int off = 32; off >= 1; off >>= 1) {
                const float s2 = __shfl_xor(ms, off);
                const int   i2 = __shfl_xor(mi, off);
                const int   p2 = __shfl_xor(mp, off);
                if (s2 > ms || (s2 == ms && i2 < mi)) { ms = s2; mi = i2; mp = p2; }
            }
            if (l == 0) { sel[r] = mi; if (mp >= 0) Ls[mp] = NEG_INF; }
        }
        __syncthreads();
    }

    // phase 3: exact fp32 rescore of 64 candidates (wave w -> candidates w, w+4, ...)
    const float* qr = Q + (size_t)q * D3;
    for (int i = w; i < C64; i += 4) {
        const int idx = sel[i];
        float a = 0.0f;
        if (idx >= 0) {
            const float* gr = G + (size_t)idx * D3;
#pragma unroll
            for (int j = 0; j < 24; ++j)
                a = __builtin_fmaf(gr[l + 64 * j], qr[l + 64 * j], a);
        }
#pragma unroll
        for (int off = 32; off >= 1; off >>= 1) a += __shfl_xor(a, off);
        if (idx < 0) a = NEG_INF;
        if (l == 0) Fs[i] = a;
    }
    __syncthreads();

    // phase 4: final top-32 over 64 rescored candidates (wave 0, register-local)
    if (t < 64) {
        float s = Fs[l]; const int id = sel[l];
        for (int r = 0; r < KK; ++r) {
            float ms = s; int mi = id;
#pragma unroll
            for (int off = 32; off >= 1; off >>= 1) {
                const float s2 = __shfl_xor(ms, off);
                const int   i2 = __shfl_xor(mi, off);
                if (s2 > ms || (s2 == ms && i2 < mi)) { ms = s2; mi = i2; }
            }
            if (l == 0) {
                out[(size_t)q * KK + r] = (float)mi;                   // best_i as float
                out[(size_t)BQ * KK + (size_t)q * KK + r] = ms;        // best_s
            }
            if (s == ms && id == mi) s = NEG_INF; // self-invalidate winner
        }
    }
}

extern "C" void kernel_launch(void* const* d_in, const int* in_sizes, int n_in,
                              void* d_out, int out_size, void* d_ws, size_t ws_size,
                              hipStream_t stream) {
    (void)in_sizes; (void)n_in; (void)out_size; (void)ws_size;
    const float* Q = (const float*)d_in[0];
    const float* G = (const float*)d_in[1];
    const int*   M = (const int*)d_in[2];
    // d_in[3] = k (fixed 32)

    unsigned short* Qbf = (unsigned short*)d_ws;                       // 768 KB
    float* cand_s = (float*)((char*)d_ws + (1u << 20));                // 8 MB
    int*   cand_i = (int*)((char*)d_ws + (1u << 20) +
                           (size_t)BQ * WB * KBP * sizeof(float));     // 8 MB
    float* out = (float*)d_out;

    hipLaunchKernelGGL(cvt_q, dim3(192), dim3(256), 0, stream, Q, Qbf);
    hipLaunchKernelGGL(score_mfma, dim3(WB), dim3(256), 0, stream, Qbf, G, M, cand_s, cand_i);
    hipLaunchKernelGGL(merge_rescore, dim3(BQ), dim3(256), 0, stream, cand_s, cand_i, Q, G, out);
}